// Round 7
// baseline (284.763 us; speedup 1.0000x reference)
//
#include <hip/hip_runtime.h>
#include <cmath>

// Problem constants (fixed by reference)
#define SS 3
#define NN 8192
#define EE 1024
#define DD 512
#define ALPHA 3.0f
// z-margin below which a row is recomputed in fp32.
// Split-bf16 z-error sigma ~= 3e-4..5e-4; 0.03 is >= 60 sigma.
// Measured rounds 3-5: ~12 flagged rows of 24576.
#define TAU 0.03f

typedef __attribute__((ext_vector_type(8))) short bf16x8;
typedef __attribute__((ext_vector_type(4))) float f32x4;
typedef __attribute__((ext_vector_type(16))) float f32x16;

#define AS1(p) ((const __attribute__((address_space(1))) void*)(p))
#define AS3(p) ((__attribute__((address_space(3))) void*)(p))

// ---------------- helpers ----------------
__device__ __forceinline__ unsigned short f2bf(float x) {
    unsigned u = __float_as_uint(x);
    return (unsigned short)((u + 0x7fffu + ((u >> 16) & 1u)) >> 16);
}
__device__ __forceinline__ float bf2f(unsigned short h) {
    return __uint_as_float(((unsigned)h) << 16);
}

__device__ __forceinline__ void gload_lds16(const unsigned short* g, unsigned short* l) {
    __builtin_amdgcn_global_load_lds(AS1(g), AS3(l), 16, 0, 0);
}

// ---------------- kernel A: fused fp32 -> (hi, lo) bf16 split for both inputs ----
__global__ __launch_bounds__(256)
void split_both_kernel(const float* __restrict__ node, const float* __restrict__ edge,
                       unsigned short* __restrict__ Ah, unsigned short* __restrict__ Al,
                       unsigned short* __restrict__ Bh, unsigned short* __restrict__ Bl)
{
    const int nA = SS * NN * DD / 4;
    const int nB = SS * EE * DD / 4;
    int i = blockIdx.x * blockDim.x + threadIdx.x;

    const float4* src;
    unsigned short* hi;
    unsigned short* lo;
    int idx;
    if (i < nA) {
        src = (const float4*)node; hi = Ah; lo = Al; idx = i;
    } else if (i < nA + nB) {
        src = (const float4*)edge; hi = Bh; lo = Bl; idx = i - nA;
    } else {
        return;
    }
    float4 v = src[idx];
    ushort4 h, l;
    h.x = f2bf(v.x); l.x = f2bf(v.x - bf2f(h.x));
    h.y = f2bf(v.y); l.y = f2bf(v.y - bf2f(h.y));
    h.z = f2bf(v.z); l.z = f2bf(v.z - bf2f(h.z));
    h.w = f2bf(v.w); l.w = f2bf(v.w - bf2f(h.w));
    ((ushort4*)hi)[idx] = h;
    ((ushort4*)lo)[idx] = l;
}

// ---------------- kernel B: split-bf16 MFMA GEMM, z = relu(alpha*sim) ----------------
// 128x256 tile (M x N), BK=32, 8 waves (2m x 4n, wave-tile 64x64),
// 32x32x16 MFMA, 3 per frag position: hh, hl, lh (fp32 accumulate).
// Grid (64,4,3) = 768 blocks = exactly 3 CU-rounds (no tail); m-fastest so the
// 4 n-blocks of an A-panel land on one XCD (ids differ by 64 = 0 mod 8).
//
// LDS: 2 buffers x 4 regions [plane(hi/lo)][khalf] x [384 rows][32B] = 96 KB.
// 32B row stride => ds_read_b128 frag reads are 8-lanes-per-4-bank-group
// balanced (full LDS BW, no swizzle needed). Each (plane,khalf) region is
// contiguous, so staging keeps gload_lds's wave-linear dest while splitting
// the K-step into 2 independently-waited phases.
//
// Counted pipeline (never vmcnt(0) in loop): phase kh of step t
//   [frag ds_reads of KH_kh(t) (staged 2 phases ago)]
//   [issue 3 gload_lds staging KH_kh(t+1)]
//   s_waitcnt vmcnt(3)   // retires the other-kh batch issued last phase+1
//   s_barrier            // makes retirement global
//   setprio(1); 12 MFMA; setprio(0)
// Every region has >=2 barriers between last read and overwrite-issue.
__global__ __launch_bounds__(512, 2)
void gemm_mfma_kernel(const unsigned short* __restrict__ Ah,
                      const unsigned short* __restrict__ Al,
                      const unsigned short* __restrict__ Bh,
                      const unsigned short* __restrict__ Bl,
                      float* __restrict__ out)
{
    const int s  = blockIdx.z;
    const int m0 = blockIdx.x * 128;   // m-fastest
    const int n0 = blockIdx.y * 256;

    const unsigned short* pAh = Ah + (size_t)s * NN * DD;
    const unsigned short* pAl = Al + (size_t)s * NN * DD;
    const unsigned short* pBh = Bh + (size_t)s * EE * DD;
    const unsigned short* pBl = Bl + (size_t)s * EE * DD;
    float* C = out + (size_t)s * NN * EE;

    // 2 x 24576 ushorts = 96 KB; buffer layout: [pl*2+kh]*6144 + row*16 + part*8
    __shared__ unsigned short lds[2 * 24576];

    const int t    = threadIdx.x;
    const int lane = t & 63;
    const int wid  = t >> 6;
    const int wm   = wid >> 2;       // 0..1: wave m-group (64 rows)
    const int wn   = wid & 3;        // 0..3: wave n-group (64 cols)
    const int fr   = lane & 31;      // row/col within 32x32 frag
    const int kp   = lane >> 5;      // k-part (0..1), 8 bf16 each

    f32x16 acc[2][2];
#pragma unroll
    for (int p = 0; p < 2; ++p)
#pragma unroll
        for (int nf = 0; nf < 2; ++nf)
#pragma unroll
            for (int r = 0; r < 16; ++r) acc[p][nf][r] = 0.f;

    // stage the (kh) half of K-step with base k0 into buffer buf.
    // 24 spans of 32 rows x 32B; span = wid*3 + i; pl = span/12; sp = span%12.
    auto issue_kh = [&](int kh, int buf, int k0) {
#pragma unroll
        for (int i = 0; i < 3; ++i) {
            const int span = wid * 3 + i;        // 0..23, wave-uniform
            const int pl   = span / 12;
            const int sp   = span % 12;
            const int r    = sp * 32 + (lane >> 1);   // 0..383
            const size_t goff = (size_t)k0 + kh * 16 + (lane & 1) * 8;
            const unsigned short* src;
            if (sp < 4) {  // rows 0..127: A
                src = (pl ? pAl : pAh) + (size_t)(m0 + r) * DD + goff;
            } else {       // rows 128..383: B (cols)
                src = (pl ? pBl : pBh) + (size_t)(n0 + r - 128) * DD + goff;
            }
            gload_lds16(src, &lds[buf * 24576 + (pl * 2 + kh) * 6144 + sp * 512 + lane * 8]);
        }
    };

    // one phase: frag reads + MFMA for k-half kh of the current step,
    // while staging the same k-half of the next step.
    auto phase = [&](int kh, int buf, int nbuf, int kn) {
        bf16x8 a[2][2], b[2][2];   // [frag][plane]
#pragma unroll
        for (int p = 0; p < 2; ++p)
#pragma unroll
            for (int pl = 0; pl < 2; ++pl) {
                const int row = wm * 64 + p * 32 + fr;
                a[p][pl] = *(const bf16x8*)&lds[buf * 24576 + (pl * 2 + kh) * 6144 + row * 16 + kp * 8];
            }
#pragma unroll
        for (int nf = 0; nf < 2; ++nf)
#pragma unroll
            for (int pl = 0; pl < 2; ++pl) {
                const int row = 128 + wn * 64 + nf * 32 + fr;
                b[nf][pl] = *(const bf16x8*)&lds[buf * 24576 + (pl * 2 + kh) * 6144 + row * 16 + kp * 8];
            }

        issue_kh(kh, nbuf, kn);

        asm volatile("s_waitcnt vmcnt(3)" ::: "memory");
        __builtin_amdgcn_s_barrier();

        __builtin_amdgcn_s_setprio(1);
#pragma unroll
        for (int p = 0; p < 2; ++p) {
            acc[p][0] = __builtin_amdgcn_mfma_f32_32x32x16_bf16(a[p][0], b[0][0], acc[p][0], 0, 0, 0);
            acc[p][1] = __builtin_amdgcn_mfma_f32_32x32x16_bf16(a[p][0], b[1][0], acc[p][1], 0, 0, 0);
            acc[p][0] = __builtin_amdgcn_mfma_f32_32x32x16_bf16(a[p][0], b[0][1], acc[p][0], 0, 0, 0);
            acc[p][1] = __builtin_amdgcn_mfma_f32_32x32x16_bf16(a[p][0], b[1][1], acc[p][1], 0, 0, 0);
            acc[p][0] = __builtin_amdgcn_mfma_f32_32x32x16_bf16(a[p][1], b[0][0], acc[p][0], 0, 0, 0);
            acc[p][1] = __builtin_amdgcn_mfma_f32_32x32x16_bf16(a[p][1], b[1][0], acc[p][1], 0, 0, 0);
        }
        __builtin_amdgcn_s_setprio(0);
    };

    // prologue: stage both halves of step 0, retire KH0, sync.
    issue_kh(0, 0, 0);
    issue_kh(1, 0, 0);
    asm volatile("s_waitcnt vmcnt(3)" ::: "memory");
    __builtin_amdgcn_s_barrier();

#pragma unroll 1
    for (int ks = 0; ks < 16; ++ks) {
        const int buf  = ks & 1;
        const int nbuf = buf ^ 1;
        const int kn   = ((ks + 1) & 15) * 32;   // ks=15 re-stages k=0 (harmless dummy)
        phase(0, buf, nbuf, kn);
        phase(1, buf, nbuf, kn);
    }

    // epilogue: z = relu(alpha*acc)
    // 32x32 C/D layout: col = lane&31, row = (reg&3) + 8*(reg>>2) + 4*(lane>>5)
#pragma unroll
    for (int p = 0; p < 2; ++p)
#pragma unroll
        for (int nf = 0; nf < 2; ++nf) {
            const int col = n0 + wn * 64 + nf * 32 + fr;
#pragma unroll
            for (int r = 0; r < 16; ++r) {
                const int row = m0 + wm * 64 + p * 32 + (r & 3) + 8 * (r >> 2) + 4 * kp;
                C[(size_t)row * EE + col] = fmaxf(ALPHA * acc[p][nf][r], 0.f);
            }
        }
}

// ---------------- kernel Z: zero the worklist counter ----------------
__global__ void zero_count_kernel(int* __restrict__ count) {
    if (threadIdx.x == 0 && blockIdx.x == 0) count[0] = 0;
}

// ---------------- kernel C: softmax threshold + borderline worklist ----------------
__global__ __launch_bounds__(256)
void softmax_threshold_flag_kernel(float* __restrict__ out,
                                   int* __restrict__ count,
                                   int* __restrict__ worklist)
{
    const int wave = threadIdx.x >> 6;
    const int lane = threadIdx.x & 63;
    const size_t row = (size_t)blockIdx.x * 4 + wave;
    float* p = out + row * EE;

    float z[16];
    float m = 0.f;  // z >= 0 (relu output)
#pragma unroll
    for (int j = 0; j < 4; ++j) {
        float4 v = *(const float4*)(p + j * 256 + lane * 4);
        z[j*4+0] = v.x; z[j*4+1] = v.y; z[j*4+2] = v.z; z[j*4+3] = v.w;
        m = fmaxf(m, fmaxf(fmaxf(v.x, v.y), fmaxf(v.z, v.w)));
    }
#pragma unroll
    for (int off = 32; off >= 1; off >>= 1)
        m = fmaxf(m, __shfl_xor(m, off, 64));

    float e[16];
    float sum = 0.f;
#pragma unroll
    for (int j = 0; j < 16; ++j) {
        e[j] = expf(z[j] - m);
        sum += e[j];
    }
#pragma unroll
    for (int off = 32; off >= 1; off >>= 1)
        sum += __shfl_xor(sum, off, 64);

    const float thr = 0.5f * sum;
    const float T   = m + logf(thr);   // z-space threshold
    int lf = 0;
#pragma unroll
    for (int j = 0; j < 16; ++j)
        lf |= (fabsf(z[j] - T) < TAU) ? 1 : 0;

#pragma unroll
    for (int j = 0; j < 4; ++j) {
        float4 o;
        o.x = (e[j*4+0] > thr) ? 1.f : 0.f;
        o.y = (e[j*4+1] > thr) ? 1.f : 0.f;
        o.z = (e[j*4+2] > thr) ? 1.f : 0.f;
        o.w = (e[j*4+3] > thr) ? 1.f : 0.f;
        *(float4*)(p + j * 256 + lane * 4) = o;
    }
    const int anyf = __any(lf);
    if (anyf && lane == 0) {
        int idx = atomicAdd(count, 1);
        worklist[idx] = (int)row;
    }
}

// ---------------- kernel D1: parallel fp32 z-recompute of worklisted rows ----
__global__ __launch_bounds__(256)
void fixup_z_kernel(const float* __restrict__ node, const float* __restrict__ edge,
                    const int* __restrict__ count, const int* __restrict__ worklist,
                    float* __restrict__ zbuf, int zcap)
{
    __shared__ float sa[DD];
    const int t    = threadIdx.x;
    const int lane = t & 63;
    const int wid  = t >> 6;

    int nwork = count[0];
    if (nwork > zcap) nwork = zcap;
    const int items = nwork * 4;

    for (int item = blockIdx.x; item < items; item += gridDim.x) {
        const int w   = item >> 2;
        const int row = worklist[w];
        const int c0  = (item & 3) * 256;
        const int s   = row / NN;
        const float* a = node + (size_t)row * DD;
        const float* B = edge + (size_t)s * EE * DD;

        __syncthreads();   // protect sa from previous item
        if (t < DD / 4) ((float4*)sa)[t] = ((const float4*)a)[t];
        __syncthreads();

        const float4 va0 = ((const float4*)sa)[lane];
        const float4 va1 = ((const float4*)sa)[64 + lane];

        const int cbase = c0 + wid * 64;
        for (int g = 0; g < 16; ++g) {
            float acc[4];
#pragma unroll
            for (int j = 0; j < 4; ++j) {
                const float* b = B + (size_t)(cbase + g * 4 + j) * DD;
                float4 b0 = *(const float4*)(b + lane * 4);
                float4 b1 = *(const float4*)(b + 256 + lane * 4);
                float av;
                av = va0.x * b0.x;
                av = fmaf(va0.y, b0.y, av);
                av = fmaf(va0.z, b0.z, av);
                av = fmaf(va0.w, b0.w, av);
                av = fmaf(va1.x, b1.x, av);
                av = fmaf(va1.y, b1.y, av);
                av = fmaf(va1.z, b1.z, av);
                av = fmaf(va1.w, b1.w, av);
                acc[j] = av;
            }
#pragma unroll
            for (int off = 32; off >= 1; off >>= 1) {
#pragma unroll
                for (int j = 0; j < 4; ++j)
                    acc[j] += __shfl_xor(acc[j], off, 64);
            }
            if (lane == 0) {
#pragma unroll
                for (int j = 0; j < 4; ++j)
                    zbuf[(size_t)w * EE + cbase + g * 4 + j] = fmaxf(ALPHA * acc[j], 0.f);
            }
        }
    }
}

// ---------------- kernel D2: softmax+threshold of recomputed rows ----------
__global__ __launch_bounds__(256)
void fixup_finish_kernel(const float* __restrict__ zbuf,
                         const int* __restrict__ count, const int* __restrict__ worklist,
                         float* __restrict__ out, int zcap)
{
    const int lane = threadIdx.x & 63;
    const int wid  = threadIdx.x >> 6;
    int nwork = count[0];
    if (nwork > zcap) nwork = zcap;

    for (int w = blockIdx.x * 4 + wid; w < nwork; w += gridDim.x * 4) {
        const int row = worklist[w];
        const float* p = zbuf + (size_t)w * EE;

        float z[16];
        float m = 0.f;
#pragma unroll
        for (int j = 0; j < 4; ++j) {
            float4 v = *(const float4*)(p + j * 256 + lane * 4);
            z[j*4+0] = v.x; z[j*4+1] = v.y; z[j*4+2] = v.z; z[j*4+3] = v.w;
            m = fmaxf(m, fmaxf(fmaxf(v.x, v.y), fmaxf(v.z, v.w)));
        }
#pragma unroll
        for (int off = 32; off >= 1; off >>= 1)
            m = fmaxf(m, __shfl_xor(m, off, 64));

        float e[16], sum = 0.f;
#pragma unroll
        for (int j = 0; j < 16; ++j) { e[j] = expf(z[j] - m); sum += e[j]; }
#pragma unroll
        for (int off = 32; off >= 1; off >>= 1)
            sum += __shfl_xor(sum, off, 64);

        const float thr = 0.5f * sum;
        float* q = out + (size_t)row * EE;
#pragma unroll
        for (int j = 0; j < 4; ++j) {
            float4 o;
            o.x = (e[j*4+0] > thr) ? 1.f : 0.f;
            o.y = (e[j*4+1] > thr) ? 1.f : 0.f;
            o.z = (e[j*4+2] > thr) ? 1.f : 0.f;
            o.w = (e[j*4+3] > thr) ? 1.f : 0.f;
            *(float4*)(q + j * 256 + lane * 4) = o;
        }
    }
}

// ---------------- kernel D3: slow-path fixup for rows beyond zcap ----------
__global__ __launch_bounds__(256)
void fixup2_kernel(const float* __restrict__ node, const float* __restrict__ edge,
                   const int* __restrict__ count, const int* __restrict__ worklist,
                   float* __restrict__ out, int start)
{
    __shared__ float sa[DD];
    __shared__ float zrow[EE];
    __shared__ float red[8];

    const int t    = threadIdx.x;
    const int lane = t & 63;
    const int wid  = t >> 6;
    const int nwork = count[0];

    for (int w = start + blockIdx.x; w < nwork; w += gridDim.x) {
        const int row = worklist[w];
        const int s = row / NN;
        const float* a = node + (size_t)row * DD;
        const float* B = edge + (size_t)s * EE * DD;

        __syncthreads();
        if (t < DD / 4) ((float4*)sa)[t] = ((const float4*)a)[t];
        __syncthreads();

        float4 va0 = ((const float4*)sa)[lane];
        float4 va1 = ((const float4*)sa)[64 + lane];

        for (int c = wid; c < EE; c += 4) {
            const float* b = B + (size_t)c * DD;
            float4 b0 = *(const float4*)(b + lane * 4);
            float4 b1 = *(const float4*)(b + 256 + lane * 4);
            float acc;
            acc = va0.x * b0.x;
            acc = fmaf(va0.y, b0.y, acc);
            acc = fmaf(va0.z, b0.z, acc);
            acc = fmaf(va0.w, b0.w, acc);
            acc = fmaf(va1.x, b1.x, acc);
            acc = fmaf(va1.y, b1.y, acc);
            acc = fmaf(va1.z, b1.z, acc);
            acc = fmaf(va1.w, b1.w, acc);
#pragma unroll
            for (int off = 32; off >= 1; off >>= 1)
                acc += __shfl_xor(acc, off, 64);
            if (lane == 0) zrow[c] = fmaxf(ALPHA * acc, 0.f);
        }
        __syncthreads();

        float z[4], m = 0.f;
#pragma unroll
        for (int j = 0; j < 4; ++j) {
            z[j] = zrow[j * 256 + t];
            m = fmaxf(m, z[j]);
        }
#pragma unroll
        for (int off = 32; off >= 1; off >>= 1)
            m = fmaxf(m, __shfl_xor(m, off, 64));
        if (lane == 0) red[wid] = m;
        __syncthreads();
        m = fmaxf(fmaxf(red[0], red[1]), fmaxf(red[2], red[3]));

        float e[4], sum = 0.f;
#pragma unroll
        for (int j = 0; j < 4; ++j) { e[j] = expf(z[j] - m); sum += e[j]; }
#pragma unroll
        for (int off = 32; off >= 1; off >>= 1)
            sum += __shfl_xor(sum, off, 64);
        if (lane == 0) red[4 + wid] = sum;
        __syncthreads();
        sum = red[4] + red[5] + red[6] + red[7];

        const float thr = 0.5f * sum;
#pragma unroll
        for (int j = 0; j < 4; ++j)
            out[(size_t)row * EE + j * 256 + t] = (e[j] > thr) ? 1.f : 0.f;
        __syncthreads();
    }
}

// ---------------- fallback fp32 path (round-0, verified) ----------------
#define BM 128
#define BN 128
#define BK 16
#define TM 8
#define TN 8

__global__ __launch_bounds__(256, 2)
void gemm_relu_kernel(const float* __restrict__ node,
                      const float* __restrict__ edge,
                      float* __restrict__ out)
{
    const int s  = blockIdx.z;
    const int m0 = blockIdx.y * BM;
    const int n0 = blockIdx.x * BN;

    const float* A = node + (size_t)s * NN * DD;
    const float* B = edge + (size_t)s * EE * DD;
    float*       C = out  + (size_t)s * NN * EE;

    __shared__ float As[BK][BM + 4];
    __shared__ float Bs[BK][BN + 4];

    const int tid = threadIdx.x;
    const int tx  = tid % 16;
    const int ty  = tid / 16;
    const int lrow = tid / 4;
    const int lcol = (tid % 4) * 4;

    float acc[TM][TN];
#pragma unroll
    for (int i = 0; i < TM; ++i)
#pragma unroll
        for (int j = 0; j < TN; ++j) acc[i][j] = 0.f;

    for (int k0 = 0; k0 < DD; k0 += BK) {
#pragma unroll
        for (int p = 0; p < 2; ++p) {
            const int r = lrow + p * 64;
            float4 v = *(const float4*)(A + (size_t)(m0 + r) * DD + k0 + lcol);
            As[lcol + 0][r] = v.x; As[lcol + 1][r] = v.y;
            As[lcol + 2][r] = v.z; As[lcol + 3][r] = v.w;
            float4 w = *(const float4*)(B + (size_t)(n0 + r) * DD + k0 + lcol);
            Bs[lcol + 0][r] = w.x; Bs[lcol + 1][r] = w.y;
            Bs[lcol + 2][r] = w.z; Bs[lcol + 3][r] = w.w;
        }
        __syncthreads();
#pragma unroll
        for (int k = 0; k < BK; ++k) {
            float a[TM], b[TN];
            float4 a0 = *(const float4*)&As[k][ty * 8];
            float4 a1 = *(const float4*)&As[k][ty * 8 + 4];
            a[0]=a0.x; a[1]=a0.y; a[2]=a0.z; a[3]=a0.w;
            a[4]=a1.x; a[5]=a1.y; a[6]=a1.z; a[7]=a1.w;
            float4 b0 = *(const float4*)&Bs[k][tx * 8];
            float4 b1 = *(const float4*)&Bs[k][tx * 8 + 4];
            b[0]=b0.x; b[1]=b0.y; b[2]=b0.z; b[3]=b0.w;
            b[4]=b1.x; b[5]=b1.y; b[6]=b1.z; b[7]=b1.w;
#pragma unroll
            for (int i = 0; i < TM; ++i)
#pragma unroll
                for (int j = 0; j < TN; ++j)
                    acc[i][j] = fmaf(a[i], b[j], acc[i][j]);
        }
        __syncthreads();
    }
#pragma unroll
    for (int i = 0; i < TM; ++i) {
        const size_t row = (size_t)(m0 + ty * 8 + i);
        float4 o0, o1;
        o0.x = fmaxf(ALPHA * acc[i][0], 0.f);
        o0.y = fmaxf(ALPHA * acc[i][1], 0.f);
        o0.z = fmaxf(ALPHA * acc[i][2], 0.f);
        o0.w = fmaxf(ALPHA * acc[i][3], 0.f);
        o1.x = fmaxf(ALPHA * acc[i][4], 0.f);
        o1.y = fmaxf(ALPHA * acc[i][5], 0.f);
        o1.z = fmaxf(ALPHA * acc[i][6], 0.f);
        o1.w = fmaxf(ALPHA * acc[i][7], 0.f);
        *(float4*)(C + row * EE + n0 + tx * 8)     = o0;
        *(float4*)(C + row * EE + n0 + tx * 8 + 4) = o1;
    }
}

__global__ __launch_bounds__(256)
void softmax_threshold_kernel(float* __restrict__ out)
{
    const int wave = threadIdx.x >> 6;
    const int lane = threadIdx.x & 63;
    const size_t row = (size_t)blockIdx.x * 4 + wave;
    float* p = out + row * EE;

    float z[16];
    float m = 0.f;
#pragma unroll
    for (int j = 0; j < 4; ++j) {
        float4 v = *(const float4*)(p + j * 256 + lane * 4);
        z[j*4+0] = v.x; z[j*4+1] = v.y; z[j*4+2] = v.z; z[j*4+3] = v.w;
        m = fmaxf(m, fmaxf(fmaxf(v.x, v.y), fmaxf(v.z, v.w)));
    }
#pragma unroll
    for (int off = 32; off >= 1; off >>= 1)
        m = fmaxf(m, __shfl_xor(m, off, 64));
    float e[16], sum = 0.f;
#pragma unroll
    for (int j = 0; j < 16; ++j) { e[j] = expf(z[j] - m); sum += e[j]; }
#pragma unroll
    for (int off = 32; off >= 1; off >>= 1)
        sum += __shfl_xor(sum, off, 64);
    const float thr = 0.5f * sum;
#pragma unroll
    for (int j = 0; j < 4; ++j) {
        float4 o;
        o.x = (e[j*4+0] > thr) ? 1.f : 0.f;
        o.y = (e[j*4+1] > thr) ? 1.f : 0.f;
        o.z = (e[j*4+2] > thr) ? 1.f : 0.f;
        o.w = (e[j*4+3] > thr) ? 1.f : 0.f;
        *(float4*)(p + j * 256 + lane * 4) = o;
    }
}

// ---------------- launch ----------------
extern "C" void kernel_launch(void* const* d_in, const int* in_sizes, int n_in,
                              void* d_out, int out_size, void* d_ws, size_t ws_size,
                              hipStream_t stream) {
    const float* node = (const float*)d_in[1];  // [S, N, D]
    const float* edge = (const float*)d_in[2];  // [S, E, D]
    float* out = (float*)d_out;                 // [S, N, E]

    const size_t SAe = (size_t)SS * NN * DD;    // node elems
    const size_t SBe = (size_t)SS * EE * DD;    // edge elems
    const size_t split_bytes = (2 * SAe + 2 * SBe) * 2;
    const size_t wl_bytes    = (size_t)(SS * NN + 1) * 4;
    const size_t base_need   = split_bytes + wl_bytes;

    if (ws_size >= base_need) {
        unsigned short* Ah = (unsigned short*)d_ws;
        unsigned short* Al = Ah + SAe;
        unsigned short* Bh = Al + SAe;
        unsigned short* Bl = Bh + SBe;
        int* count    = (int*)(Bl + SBe);
        int* worklist = count + 1;

        // z-scratch for the parallel fixup, after the base region (256B aligned)
        const size_t zoff = (base_need + 255) & ~(size_t)255;
        int zcap = 0;
        if (ws_size > zoff) {
            size_t zc = (ws_size - zoff) / ((size_t)EE * 4);
            zcap = (int)(zc > 4096 ? 4096 : zc);
        }
        float* zbuf = (float*)((char*)d_ws + zoff);

        const int n4 = (int)((SAe + SBe) / 4);
        split_both_kernel<<<(n4 + 255) / 256, 256, 0, stream>>>(node, edge, Ah, Al, Bh, Bl);

        zero_count_kernel<<<1, 64, 0, stream>>>(count);

        dim3 g1(NN / 128, EE / 256, SS);   // (64, 4, 3) = 768 blocks: 3 clean CU-rounds
        gemm_mfma_kernel<<<g1, 512, 0, stream>>>(Ah, Al, Bh, Bl, out);

        softmax_threshold_flag_kernel<<<(SS * NN) / 4, 256, 0, stream>>>(out, count, worklist);

        if (zcap > 0) {
            fixup_z_kernel<<<1024, 256, 0, stream>>>(node, edge, count, worklist, zbuf, zcap);
            fixup_finish_kernel<<<64, 256, 0, stream>>>(zbuf, count, worklist, out, zcap);
        }
        // rows beyond zcap (never in practice): slow in-block path
        fixup2_kernel<<<512, 256, 0, stream>>>(node, edge, count, worklist, out, zcap);
    } else {
        dim3 g1(EE / BN, NN / BM, SS);
        gemm_relu_kernel<<<g1, 256, 0, stream>>>(node, edge, out);
        softmax_threshold_kernel<<<(SS * NN) / 4, 256, 0, stream>>>(out);
    }
}

// Round 8
// 183.131 us; speedup vs baseline: 1.5550x; 1.5550x over previous
//
#include <hip/hip_runtime.h>
#include <cmath>

// Problem constants (fixed by reference)
#define SS 3
#define NN 8192
#define EE 1024
#define DD 512
#define ALPHA 3.0f
// z-margin below which a row is recomputed in fp32.
// Split-bf16 z-error sigma ~= 3e-4..5e-4; 0.03 is >= 60 sigma.
// Measured rounds 3-5: ~12 flagged rows of 24576.
#define TAU 0.03f

typedef __attribute__((ext_vector_type(8))) short bf16x8;
typedef __attribute__((ext_vector_type(4))) float f32x4;
typedef __attribute__((ext_vector_type(16))) float f32x16;

#define AS1(p) ((const __attribute__((address_space(1))) void*)(p))
#define AS3(p) ((__attribute__((address_space(3))) void*)(p))

// ---------------- helpers ----------------
__device__ __forceinline__ unsigned short f2bf(float x) {
    unsigned u = __float_as_uint(x);
    return (unsigned short)((u + 0x7fffu + ((u >> 16) & 1u)) >> 16);
}
__device__ __forceinline__ float bf2f(unsigned short h) {
    return __uint_as_float(((unsigned)h) << 16);
}

__device__ __forceinline__ void gload_lds16(const unsigned short* g, unsigned short* l) {
    __builtin_amdgcn_global_load_lds(AS1(g), AS3(l), 16, 0, 0);
}

// ---------------- kernel A: fused fp32 -> (hi, lo) bf16 split for both inputs ----
__global__ __launch_bounds__(256)
void split_both_kernel(const float* __restrict__ node, const float* __restrict__ edge,
                       unsigned short* __restrict__ Ah, unsigned short* __restrict__ Al,
                       unsigned short* __restrict__ Bh, unsigned short* __restrict__ Bl)
{
    const int nA = SS * NN * DD / 4;
    const int nB = SS * EE * DD / 4;
    int i = blockIdx.x * blockDim.x + threadIdx.x;

    const float4* src;
    unsigned short* hi;
    unsigned short* lo;
    int idx;
    if (i < nA) {
        src = (const float4*)node; hi = Ah; lo = Al; idx = i;
    } else if (i < nA + nB) {
        src = (const float4*)edge; hi = Bh; lo = Bl; idx = i - nA;
    } else {
        return;
    }
    float4 v = src[idx];
    ushort4 h, l;
    h.x = f2bf(v.x); l.x = f2bf(v.x - bf2f(h.x));
    h.y = f2bf(v.y); l.y = f2bf(v.y - bf2f(h.y));
    h.z = f2bf(v.z); l.z = f2bf(v.z - bf2f(h.z));
    h.w = f2bf(v.w); l.w = f2bf(v.w - bf2f(h.w));
    ((ushort4*)hi)[idx] = h;
    ((ushort4*)lo)[idx] = l;
}

// ---------------- kernel B: split-bf16 MFMA GEMM, z = relu(alpha*sim) ----------------
// Round-5 verified structure (128x128 tile, BK=32, 4 waves, 2-barrier K-loop,
// m-fastest grid for XCD A-panel L2 locality) with ONE change: 32x32x16 MFMA
// and a frag-linear LDS layout.
//
// LDS = 32 chunks x 1KB. Chunk = one MFMA fragment operand for one
// (plane, k-sub, frag) triple; within a chunk, lane l's 16B sit at l*16
// (consecutive per lane -> conflict-free ds_read_b128 by construction).
// gload_lds dest is base + lane*16 (linear, HW-required); the per-lane GLOBAL
// source does the fragment gather: row = frag*32 + (lane&31),
// k = k0 + ksub*16 + (lane>>5)*8 (both-sides-or-neither rule).
//   A chunks c=0..15 : pl=c>>3, ksub=(c>>2)&1, mf=c&3
//   B chunks c=16..31: pl=(c-16)>>3, ksub=((c-16)>>2)&1, nf=(c-16)&3
// Per wave-K-step: 16 ds_read_b128 + 24 v_mfma_f32_32x32x16_bf16
// (3 terms hh,hl,lh per frag position, fp32 accumulate).
__global__ __launch_bounds__(256)
void gemm_mfma_kernel(const unsigned short* __restrict__ Ah,
                      const unsigned short* __restrict__ Al,
                      const unsigned short* __restrict__ Bh,
                      const unsigned short* __restrict__ Bl,
                      float* __restrict__ out)
{
    const int s  = blockIdx.z;
    const int m0 = blockIdx.x * 128;   // m-fastest for XCD A-panel locality
    const int n0 = blockIdx.y * 128;

    const unsigned short* pAh = Ah + (size_t)s * NN * DD;
    const unsigned short* pAl = Al + (size_t)s * NN * DD;
    const unsigned short* pBh = Bh + (size_t)s * EE * DD;
    const unsigned short* pBl = Bl + (size_t)s * EE * DD;
    float* C = out + (size_t)s * NN * EE;

    __shared__ unsigned short lds[32 * 512];   // 32 KB

    const int t    = threadIdx.x;
    const int lane = t & 63;
    const int wid  = t >> 6;
    const int wm   = wid >> 1;       // wave m-group (0..1), 64 rows
    const int wn   = wid & 1;        // wave n-group (0..1), 64 cols
    const int fr   = lane & 31;      // row/col within 32x32 frag
    const int kp   = lane >> 5;      // k-part (0..1), 8 bf16 each

    f32x16 acc[2][2];
#pragma unroll
    for (int p = 0; p < 2; ++p)
#pragma unroll
        for (int nf = 0; nf < 2; ++nf)
#pragma unroll
            for (int r = 0; r < 16; ++r) acc[p][nf][r] = 0.f;

    for (int k0 = 0; k0 < DD; k0 += 32) {
        // stage 32 chunks, 8 gload_lds per wave (c = wid*8+i is wave-uniform)
#pragma unroll
        for (int i = 0; i < 8; ++i) {
            const int c = wid * 8 + i;
            const unsigned short* src;
            if (c < 16) {
                const int pl = c >> 3;
                const int ks = (c >> 2) & 1;
                const int mf = c & 3;
                src = (pl ? pAl : pAh) + (size_t)(m0 + mf * 32 + fr) * DD + k0 + ks * 16 + kp * 8;
            } else {
                const int c2 = c - 16;
                const int pl = c2 >> 3;
                const int ks = (c2 >> 2) & 1;
                const int nf = c2 & 3;
                src = (pl ? pBl : pBh) + (size_t)(n0 + nf * 32 + fr) * DD + k0 + ks * 16 + kp * 8;
            }
            gload_lds16(src, &lds[c * 512 + lane * 8]);
        }
        __syncthreads();

#pragma unroll
        for (int ks = 0; ks < 2; ++ks) {
            bf16x8 a[2][2], b[2][2];   // [frag][plane]
#pragma unroll
            for (int p = 0; p < 2; ++p)
#pragma unroll
                for (int pl = 0; pl < 2; ++pl)
                    a[p][pl] = *(const bf16x8*)&lds[(pl * 8 + ks * 4 + (wm * 2 + p)) * 512 + lane * 8];
#pragma unroll
            for (int nf = 0; nf < 2; ++nf)
#pragma unroll
                for (int pl = 0; pl < 2; ++pl)
                    b[nf][pl] = *(const bf16x8*)&lds[(16 + pl * 8 + ks * 4 + (wn * 2 + nf)) * 512 + lane * 8];

#pragma unroll
            for (int p = 0; p < 2; ++p)
#pragma unroll
                for (int nf = 0; nf < 2; ++nf) {
                    acc[p][nf] = __builtin_amdgcn_mfma_f32_32x32x16_bf16(a[p][0], b[nf][0], acc[p][nf], 0, 0, 0);
                    acc[p][nf] = __builtin_amdgcn_mfma_f32_32x32x16_bf16(a[p][0], b[nf][1], acc[p][nf], 0, 0, 0);
                    acc[p][nf] = __builtin_amdgcn_mfma_f32_32x32x16_bf16(a[p][1], b[nf][0], acc[p][nf], 0, 0, 0);
                }
        }
        __syncthreads();
    }

    // epilogue: z = relu(alpha*acc)
    // 32x32 C/D layout: col = lane&31, row = (reg&3) + 8*(reg>>2) + 4*(lane>>5)
#pragma unroll
    for (int p = 0; p < 2; ++p)
#pragma unroll
        for (int nf = 0; nf < 2; ++nf) {
            const int col = n0 + wn * 64 + nf * 32 + fr;
#pragma unroll
            for (int r = 0; r < 16; ++r) {
                const int row = m0 + wm * 64 + p * 32 + (r & 3) + 8 * (r >> 2) + 4 * kp;
                C[(size_t)row * EE + col] = fmaxf(ALPHA * acc[p][nf][r], 0.f);
            }
        }
}

// ---------------- kernel Z: zero the worklist counter ----------------
__global__ void zero_count_kernel(int* __restrict__ count) {
    if (threadIdx.x == 0 && blockIdx.x == 0) count[0] = 0;
}

// ---------------- kernel C: softmax threshold + borderline worklist ----------------
__global__ __launch_bounds__(256)
void softmax_threshold_flag_kernel(float* __restrict__ out,
                                   int* __restrict__ count,
                                   int* __restrict__ worklist)
{
    const int wave = threadIdx.x >> 6;
    const int lane = threadIdx.x & 63;
    const size_t row = (size_t)blockIdx.x * 4 + wave;
    float* p = out + row * EE;

    float z[16];
    float m = 0.f;  // z >= 0 (relu output)
#pragma unroll
    for (int j = 0; j < 4; ++j) {
        float4 v = *(const float4*)(p + j * 256 + lane * 4);
        z[j*4+0] = v.x; z[j*4+1] = v.y; z[j*4+2] = v.z; z[j*4+3] = v.w;
        m = fmaxf(m, fmaxf(fmaxf(v.x, v.y), fmaxf(v.z, v.w)));
    }
#pragma unroll
    for (int off = 32; off >= 1; off >>= 1)
        m = fmaxf(m, __shfl_xor(m, off, 64));

    float e[16];
    float sum = 0.f;
#pragma unroll
    for (int j = 0; j < 16; ++j) {
        e[j] = expf(z[j] - m);
        sum += e[j];
    }
#pragma unroll
    for (int off = 32; off >= 1; off >>= 1)
        sum += __shfl_xor(sum, off, 64);

    const float thr = 0.5f * sum;
    const float T   = m + logf(thr);   // z-space threshold
    int lf = 0;
#pragma unroll
    for (int j = 0; j < 16; ++j)
        lf |= (fabsf(z[j] - T) < TAU) ? 1 : 0;

#pragma unroll
    for (int j = 0; j < 4; ++j) {
        float4 o;
        o.x = (e[j*4+0] > thr) ? 1.f : 0.f;
        o.y = (e[j*4+1] > thr) ? 1.f : 0.f;
        o.z = (e[j*4+2] > thr) ? 1.f : 0.f;
        o.w = (e[j*4+3] > thr) ? 1.f : 0.f;
        *(float4*)(p + j * 256 + lane * 4) = o;
    }
    const int anyf = __any(lf);
    if (anyf && lane == 0) {
        int idx = atomicAdd(count, 1);
        worklist[idx] = (int)row;
    }
}

// ---------------- kernel D1: parallel fp32 z-recompute of worklisted rows ----
__global__ __launch_bounds__(256)
void fixup_z_kernel(const float* __restrict__ node, const float* __restrict__ edge,
                    const int* __restrict__ count, const int* __restrict__ worklist,
                    float* __restrict__ zbuf, int zcap)
{
    __shared__ float sa[DD];
    const int t    = threadIdx.x;
    const int lane = t & 63;
    const int wid  = t >> 6;

    int nwork = count[0];
    if (nwork > zcap) nwork = zcap;
    const int items = nwork * 4;

    for (int item = blockIdx.x; item < items; item += gridDim.x) {
        const int w   = item >> 2;
        const int row = worklist[w];
        const int c0  = (item & 3) * 256;
        const int s   = row / NN;
        const float* a = node + (size_t)row * DD;
        const float* B = edge + (size_t)s * EE * DD;

        __syncthreads();   // protect sa from previous item
        if (t < DD / 4) ((float4*)sa)[t] = ((const float4*)a)[t];
        __syncthreads();

        const float4 va0 = ((const float4*)sa)[lane];
        const float4 va1 = ((const float4*)sa)[64 + lane];

        const int cbase = c0 + wid * 64;
        for (int g = 0; g < 16; ++g) {
            float acc[4];
#pragma unroll
            for (int j = 0; j < 4; ++j) {
                const float* b = B + (size_t)(cbase + g * 4 + j) * DD;
                float4 b0 = *(const float4*)(b + lane * 4);
                float4 b1 = *(const float4*)(b + 256 + lane * 4);
                float av;
                av = va0.x * b0.x;
                av = fmaf(va0.y, b0.y, av);
                av = fmaf(va0.z, b0.z, av);
                av = fmaf(va0.w, b0.w, av);
                av = fmaf(va1.x, b1.x, av);
                av = fmaf(va1.y, b1.y, av);
                av = fmaf(va1.z, b1.z, av);
                av = fmaf(va1.w, b1.w, av);
                acc[j] = av;
            }
#pragma unroll
            for (int off = 32; off >= 1; off >>= 1) {
#pragma unroll
                for (int j = 0; j < 4; ++j)
                    acc[j] += __shfl_xor(acc[j], off, 64);
            }
            if (lane == 0) {
#pragma unroll
                for (int j = 0; j < 4; ++j)
                    zbuf[(size_t)w * EE + cbase + g * 4 + j] = fmaxf(ALPHA * acc[j], 0.f);
            }
        }
    }
}

// ---------------- kernel D2: softmax+threshold of recomputed rows ----------
__global__ __launch_bounds__(256)
void fixup_finish_kernel(const float* __restrict__ zbuf,
                         const int* __restrict__ count, const int* __restrict__ worklist,
                         float* __restrict__ out, int zcap)
{
    const int lane = threadIdx.x & 63;
    const int wid  = threadIdx.x >> 6;
    int nwork = count[0];
    if (nwork > zcap) nwork = zcap;

    for (int w = blockIdx.x * 4 + wid; w < nwork; w += gridDim.x * 4) {
        const int row = worklist[w];
        const float* p = zbuf + (size_t)w * EE;

        float z[16];
        float m = 0.f;
#pragma unroll
        for (int j = 0; j < 4; ++j) {
            float4 v = *(const float4*)(p + j * 256 + lane * 4);
            z[j*4+0] = v.x; z[j*4+1] = v.y; z[j*4+2] = v.z; z[j*4+3] = v.w;
            m = fmaxf(m, fmaxf(fmaxf(v.x, v.y), fmaxf(v.z, v.w)));
        }
#pragma unroll
        for (int off = 32; off >= 1; off >>= 1)
            m = fmaxf(m, __shfl_xor(m, off, 64));

        float e[16], sum = 0.f;
#pragma unroll
        for (int j = 0; j < 16; ++j) { e[j] = expf(z[j] - m); sum += e[j]; }
#pragma unroll
        for (int off = 32; off >= 1; off >>= 1)
            sum += __shfl_xor(sum, off, 64);

        const float thr = 0.5f * sum;
        float* q = out + (size_t)row * EE;
#pragma unroll
        for (int j = 0; j < 4; ++j) {
            float4 o;
            o.x = (e[j*4+0] > thr) ? 1.f : 0.f;
            o.y = (e[j*4+1] > thr) ? 1.f : 0.f;
            o.z = (e[j*4+2] > thr) ? 1.f : 0.f;
            o.w = (e[j*4+3] > thr) ? 1.f : 0.f;
            *(float4*)(q + j * 256 + lane * 4) = o;
        }
    }
}

// ---------------- kernel D3: slow-path fixup for rows beyond zcap ----------
__global__ __launch_bounds__(256)
void fixup2_kernel(const float* __restrict__ node, const float* __restrict__ edge,
                   const int* __restrict__ count, const int* __restrict__ worklist,
                   float* __restrict__ out, int start)
{
    __shared__ float sa[DD];
    __shared__ float zrow[EE];
    __shared__ float red[8];

    const int t    = threadIdx.x;
    const int lane = t & 63;
    const int wid  = t >> 6;
    const int nwork = count[0];

    for (int w = start + blockIdx.x; w < nwork; w += gridDim.x) {
        const int row = worklist[w];
        const int s = row / NN;
        const float* a = node + (size_t)row * DD;
        const float* B = edge + (size_t)s * EE * DD;

        __syncthreads();
        if (t < DD / 4) ((float4*)sa)[t] = ((const float4*)a)[t];
        __syncthreads();

        float4 va0 = ((const float4*)sa)[lane];
        float4 va1 = ((const float4*)sa)[64 + lane];

        for (int c = wid; c < EE; c += 4) {
            const float* b = B + (size_t)c * DD;
            float4 b0 = *(const float4*)(b + lane * 4);
            float4 b1 = *(const float4*)(b + 256 + lane * 4);
            float acc;
            acc = va0.x * b0.x;
            acc = fmaf(va0.y, b0.y, acc);
            acc = fmaf(va0.z, b0.z, acc);
            acc = fmaf(va0.w, b0.w, acc);
            acc = fmaf(va1.x, b1.x, acc);
            acc = fmaf(va1.y, b1.y, acc);
            acc = fmaf(va1.z, b1.z, acc);
            acc = fmaf(va1.w, b1.w, acc);
#pragma unroll
            for (int off = 32; off >= 1; off >>= 1)
                acc += __shfl_xor(acc, off, 64);
            if (lane == 0) zrow[c] = fmaxf(ALPHA * acc, 0.f);
        }
        __syncthreads();

        float z[4], m = 0.f;
#pragma unroll
        for (int j = 0; j < 4; ++j) {
            z[j] = zrow[j * 256 + t];
            m = fmaxf(m, z[j]);
        }
#pragma unroll
        for (int off = 32; off >= 1; off >>= 1)
            m = fmaxf(m, __shfl_xor(m, off, 64));
        if (lane == 0) red[wid] = m;
        __syncthreads();
        m = fmaxf(fmaxf(red[0], red[1]), fmaxf(red[2], red[3]));

        float e[4], sum = 0.f;
#pragma unroll
        for (int j = 0; j < 4; ++j) { e[j] = expf(z[j] - m); sum += e[j]; }
#pragma unroll
        for (int off = 32; off >= 1; off >>= 1)
            sum += __shfl_xor(sum, off, 64);
        if (lane == 0) red[4 + wid] = sum;
        __syncthreads();
        sum = red[4] + red[5] + red[6] + red[7];

        const float thr = 0.5f * sum;
#pragma unroll
        for (int j = 0; j < 4; ++j)
            out[(size_t)row * EE + j * 256 + t] = (e[j] > thr) ? 1.f : 0.f;
        __syncthreads();
    }
}

// ---------------- fallback fp32 path (round-0, verified) ----------------
#define BM 128
#define BN 128
#define BK 16
#define TM 8
#define TN 8

__global__ __launch_bounds__(256, 2)
void gemm_relu_kernel(const float* __restrict__ node,
                      const float* __restrict__ edge,
                      float* __restrict__ out)
{
    const int s  = blockIdx.z;
    const int m0 = blockIdx.y * BM;
    const int n0 = blockIdx.x * BN;

    const float* A = node + (size_t)s * NN * DD;
    const float* B = edge + (size_t)s * EE * DD;
    float*       C = out  + (size_t)s * NN * EE;

    __shared__ float As[BK][BM + 4];
    __shared__ float Bs[BK][BN + 4];

    const int tid = threadIdx.x;
    const int tx  = tid % 16;
    const int ty  = tid / 16;
    const int lrow = tid / 4;
    const int lcol = (tid % 4) * 4;

    float acc[TM][TN];
#pragma unroll
    for (int i = 0; i < TM; ++i)
#pragma unroll
        for (int j = 0; j < TN; ++j) acc[i][j] = 0.f;

    for (int k0 = 0; k0 < DD; k0 += BK) {
#pragma unroll
        for (int p = 0; p < 2; ++p) {
            const int r = lrow + p * 64;
            float4 v = *(const float4*)(A + (size_t)(m0 + r) * DD + k0 + lcol);
            As[lcol + 0][r] = v.x; As[lcol + 1][r] = v.y;
            As[lcol + 2][r] = v.z; As[lcol + 3][r] = v.w;
            float4 w = *(const float4*)(B + (size_t)(n0 + r) * DD + k0 + lcol);
            Bs[lcol + 0][r] = w.x; Bs[lcol + 1][r] = w.y;
            Bs[lcol + 2][r] = w.z; Bs[lcol + 3][r] = w.w;
        }
        __syncthreads();
#pragma unroll
        for (int k = 0; k < BK; ++k) {
            float a[TM], b[TN];
            float4 a0 = *(const float4*)&As[k][ty * 8];
            float4 a1 = *(const float4*)&As[k][ty * 8 + 4];
            a[0]=a0.x; a[1]=a0.y; a[2]=a0.z; a[3]=a0.w;
            a[4]=a1.x; a[5]=a1.y; a[6]=a1.z; a[7]=a1.w;
            float4 b0 = *(const float4*)&Bs[k][tx * 8];
            float4 b1 = *(const float4*)&Bs[k][tx * 8 + 4];
            b[0]=b0.x; b[1]=b0.y; b[2]=b0.z; b[3]=b0.w;
            b[4]=b1.x; b[5]=b1.y; b[6]=b1.z; b[7]=b1.w;
#pragma unroll
            for (int i = 0; i < TM; ++i)
#pragma unroll
                for (int j = 0; j < TN; ++j)
                    acc[i][j] = fmaf(a[i], b[j], acc[i][j]);
        }
        __syncthreads();
    }
#pragma unroll
    for (int i = 0; i < TM; ++i) {
        const size_t row = (size_t)(m0 + ty * 8 + i);
        float4 o0, o1;
        o0.x = fmaxf(ALPHA * acc[i][0], 0.f);
        o0.y = fmaxf(ALPHA * acc[i][1], 0.f);
        o0.z = fmaxf(ALPHA * acc[i][2], 0.f);
        o0.w = fmaxf(ALPHA * acc[i][3], 0.f);
        o1.x = fmaxf(ALPHA * acc[i][4], 0.f);
        o1.y = fmaxf(ALPHA * acc[i][5], 0.f);
        o1.z = fmaxf(ALPHA * acc[i][6], 0.f);
        o1.w = fmaxf(ALPHA * acc[i][7], 0.f);
        *(float4*)(C + row * EE + n0 + tx * 8)     = o0;
        *(float4*)(C + row * EE + n0 + tx * 8 + 4) = o1;
    }
}

__global__ __launch_bounds__(256)
void softmax_threshold_kernel(float* __restrict__ out)
{
    const int wave = threadIdx.x >> 6;
    const int lane = threadIdx.x & 63;
    const size_t row = (size_t)blockIdx.x * 4 + wave;
    float* p = out + row * EE;

    float z[16];
    float m = 0.f;
#pragma unroll
    for (int j = 0; j < 4; ++j) {
        float4 v = *(const float4*)(p + j * 256 + lane * 4);
        z[j*4+0] = v.x; z[j*4+1] = v.y; z[j*4+2] = v.z; z[j*4+3] = v.w;
        m = fmaxf(m, fmaxf(fmaxf(v.x, v.y), fmaxf(v.z, v.w)));
    }
#pragma unroll
    for (int off = 32; off >= 1; off >>= 1)
        m = fmaxf(m, __shfl_xor(m, off, 64));
    float e[16], sum = 0.f;
#pragma unroll
    for (int j = 0; j < 16; ++j) { e[j] = expf(z[j] - m); sum += e[j]; }
#pragma unroll
    for (int off = 32; off >= 1; off >>= 1)
        sum += __shfl_xor(sum, off, 64);
    const float thr = 0.5f * sum;
#pragma unroll
    for (int j = 0; j < 4; ++j) {
        float4 o;
        o.x = (e[j*4+0] > thr) ? 1.f : 0.f;
        o.y = (e[j*4+1] > thr) ? 1.f : 0.f;
        o.z = (e[j*4+2] > thr) ? 1.f : 0.f;
        o.w = (e[j*4+3] > thr) ? 1.f : 0.f;
        *(float4*)(p + j * 256 + lane * 4) = o;
    }
}

// ---------------- launch ----------------
extern "C" void kernel_launch(void* const* d_in, const int* in_sizes, int n_in,
                              void* d_out, int out_size, void* d_ws, size_t ws_size,
                              hipStream_t stream) {
    const float* node = (const float*)d_in[1];  // [S, N, D]
    const float* edge = (const float*)d_in[2];  // [S, E, D]
    float* out = (float*)d_out;                 // [S, N, E]

    const size_t SAe = (size_t)SS * NN * DD;    // node elems
    const size_t SBe = (size_t)SS * EE * DD;    // edge elems
    const size_t split_bytes = (2 * SAe + 2 * SBe) * 2;
    const size_t wl_bytes    = (size_t)(SS * NN + 1) * 4;
    const size_t base_need   = split_bytes + wl_bytes;

    if (ws_size >= base_need) {
        unsigned short* Ah = (unsigned short*)d_ws;
        unsigned short* Al = Ah + SAe;
        unsigned short* Bh = Al + SAe;
        unsigned short* Bl = Bh + SBe;
        int* count    = (int*)(Bl + SBe);
        int* worklist = count + 1;

        // z-scratch for the parallel fixup, after the base region (256B aligned)
        const size_t zoff = (base_need + 255) & ~(size_t)255;
        int zcap = 0;
        if (ws_size > zoff) {
            size_t zc = (ws_size - zoff) / ((size_t)EE * 4);
            zcap = (int)(zc > 4096 ? 4096 : zc);
        }
        float* zbuf = (float*)((char*)d_ws + zoff);

        const int n4 = (int)((SAe + SBe) / 4);
        split_both_kernel<<<(n4 + 255) / 256, 256, 0, stream>>>(node, edge, Ah, Al, Bh, Bl);

        zero_count_kernel<<<1, 64, 0, stream>>>(count);

        dim3 g1(NN / 128, EE / 128, SS);   // (64, 8, 3): m-fastest, A-panel on one XCD
        gemm_mfma_kernel<<<g1, 256, 0, stream>>>(Ah, Al, Bh, Bl, out);

        softmax_threshold_flag_kernel<<<(SS * NN) / 4, 256, 0, stream>>>(out, count, worklist);

        if (zcap > 0) {
            fixup_z_kernel<<<1024, 256, 0, stream>>>(node, edge, count, worklist, zbuf, zcap);
            fixup_finish_kernel<<<64, 256, 0, stream>>>(zbuf, count, worklist, out, zcap);
        }
        // rows beyond zcap (never in practice): slow in-block path
        fixup2_kernel<<<512, 256, 0, stream>>>(node, edge, count, worklist, out, zcap);
    } else {
        dim3 g1(EE / BN, NN / BM, SS);
        gemm_relu_kernel<<<g1, 256, 0, stream>>>(node, edge, out);
        softmax_threshold_kernel<<<(SS * NN) / 4, 256, 0, stream>>>(out);
    }
}

// Round 9
// 161.338 us; speedup vs baseline: 1.7650x; 1.1351x over previous
//
#include <hip/hip_runtime.h>
#include <cmath>

// Problem constants (fixed by reference)
#define SS 3
#define NN 8192
#define EE 1024
#define DD 512
#define ALPHA 3.0f
// z-margin below which a row is recomputed in fp32.
// Split-bf16 z-error sigma ~= 3e-4..5e-4; 0.03 is >= 60 sigma.
// Measured rounds 3-5: ~12 flagged rows of 24576.
#define TAU 0.03f

typedef __attribute__((ext_vector_type(8))) short bf16x8;
typedef __attribute__((ext_vector_type(4))) float f32x4;
typedef __attribute__((ext_vector_type(16))) float f32x16;

#define AS1(p) ((const __attribute__((address_space(1))) void*)(p))
#define AS3(p) ((__attribute__((address_space(3))) void*)(p))

// ---------------- helpers ----------------
__device__ __forceinline__ unsigned short f2bf(float x) {
    unsigned u = __float_as_uint(x);
    return (unsigned short)((u + 0x7fffu + ((u >> 16) & 1u)) >> 16);
}
__device__ __forceinline__ float bf2f(unsigned short h) {
    return __uint_as_float(((unsigned)h) << 16);
}

__device__ __forceinline__ void gload_lds16(const unsigned short* g, unsigned short* l) {
    __builtin_amdgcn_global_load_lds(AS1(g), AS3(l), 16, 0, 0);
}

// ---------------- kernel A: fused fp32 -> (hi, lo) bf16 split for both inputs ----
__global__ __launch_bounds__(256)
void split_both_kernel(const float* __restrict__ node, const float* __restrict__ edge,
                       unsigned short* __restrict__ Ah, unsigned short* __restrict__ Al,
                       unsigned short* __restrict__ Bh, unsigned short* __restrict__ Bl)
{
    const int nA = SS * NN * DD / 4;
    const int nB = SS * EE * DD / 4;
    int i = blockIdx.x * blockDim.x + threadIdx.x;

    const float4* src;
    unsigned short* hi;
    unsigned short* lo;
    int idx;
    if (i < nA) {
        src = (const float4*)node; hi = Ah; lo = Al; idx = i;
    } else if (i < nA + nB) {
        src = (const float4*)edge; hi = Bh; lo = Bl; idx = i - nA;
    } else {
        return;
    }
    float4 v = src[idx];
    ushort4 h, l;
    h.x = f2bf(v.x); l.x = f2bf(v.x - bf2f(h.x));
    h.y = f2bf(v.y); l.y = f2bf(v.y - bf2f(h.y));
    h.z = f2bf(v.z); l.z = f2bf(v.z - bf2f(h.z));
    h.w = f2bf(v.w); l.w = f2bf(v.w - bf2f(h.w));
    ((ushort4*)hi)[idx] = h;
    ((ushort4*)lo)[idx] = l;
}

// ---------------- kernel B: split-bf16 MFMA GEMM, z = relu(alpha*sim) ----------------
// Round-5 verified structure: 128x128 tile, BK=32, 4 waves, 2-barrier K-loop,
// m-fastest grid (XCD A-panel L2 locality), coalesced staging with
// slot = j ^ (row&7) chunk swizzle (verified 0 conflicts, FETCH 49MB).
// ONE change vs round 5: the compute consumes the SAME LDS layout with
// v_mfma_f32_32x32x16_bf16 (m119: 4060 vs 3378 FLOP/cyc/CU) -- wave tile
// 64x64 = 2x2 32x32 frags, 16 ds_read_b128 + 24 MFMA per wave-K-step
// (3 terms hh,hl,lh per position, fp32 accumulate).
// Frag read: lane l -> row base+p*32+(l&31), hi chunk (ks*2+kp), lo chunk
// +4, slot = chunk ^ (row&7); row bank-starts cycle {0,20,8,28,16,4,24,12}
// -> every bank-group hit exactly 8x per wave access (optimal).
// 32x32 C/D mapping verified on-device in round 8 (absmax 0).
__global__ __launch_bounds__(256)
void gemm_mfma_kernel(const unsigned short* __restrict__ Ah,
                      const unsigned short* __restrict__ Al,
                      const unsigned short* __restrict__ Bh,
                      const unsigned short* __restrict__ Bl,
                      float* __restrict__ out)
{
    const int s  = blockIdx.z;
    const int m0 = blockIdx.x * 128;   // m-fastest for XCD A-panel locality
    const int n0 = blockIdx.y * 128;

    const unsigned short* pAh = Ah + (size_t)s * NN * DD;
    const unsigned short* pAl = Al + (size_t)s * NN * DD;
    const unsigned short* pBh = Bh + (size_t)s * EE * DD;
    const unsigned short* pBl = Bl + (size_t)s * EE * DD;
    float* C = out + (size_t)s * NN * EE;

    // 2 planes (A,B) of [128 rows][8 chunks][8 ushorts] = 2 x 16KB
    __shared__ unsigned short lds[2 * 1024 * 8];

    const int t    = threadIdx.x;
    const int lane = t & 63;
    const int wid  = t >> 6;
    const int wm   = wid >> 1;       // wave row (0..1), 64 rows
    const int wn   = wid & 1;        // wave col (0..1), 64 cols
    const int fr   = lane & 31;      // row/col within 32x32 frag
    const int kp   = lane >> 5;      // k-part (0..1), 8 bf16 each

    f32x16 acc[2][2];
#pragma unroll
    for (int p = 0; p < 2; ++p)
#pragma unroll
        for (int nf = 0; nf < 2; ++nf)
#pragma unroll
            for (int r = 0; r < 16; ++r) acc[p][nf][r] = 0.f;

    for (int k0 = 0; k0 < DD; k0 += 32) {
        // stage 2048 chunks of 16B (A: 0..1023, B: 1024..2047), 8 per thread.
        // LDS dest linear in chunk id; global source picks chunk j = slot ^ (row&7),
        // j<4 -> hi chunk j, j>=4 -> lo chunk j-4.  (byte-identical to round 5)
#pragma unroll
        for (int i = 0; i < 8; ++i) {
            const int c    = i * 256 + t;
            const int pc   = c & 1023;
            const int row  = pc >> 3;
            const int slot = pc & 7;
            const int j    = slot ^ (row & 7);
            const unsigned short* src;
            if (c < 1024) {
                src = (j < 4) ? pAh + (size_t)(m0 + row) * DD + k0 + j * 8
                              : pAl + (size_t)(m0 + row) * DD + k0 + (j - 4) * 8;
            } else {
                src = (j < 4) ? pBh + (size_t)(n0 + row) * DD + k0 + j * 8
                              : pBl + (size_t)(n0 + row) * DD + k0 + (j - 4) * 8;
            }
            gload_lds16(src, &lds[c * 8]);
        }
        __syncthreads();

#pragma unroll
        for (int ks = 0; ks < 2; ++ks) {
            const int ch = ks * 2 + kp;   // hi chunk index for this lane's k 16B
            bf16x8 a[2][2], b[2][2];      // [frag][plane]
#pragma unroll
            for (int p = 0; p < 2; ++p) {
                const int r = wm * 64 + p * 32 + fr;
                a[p][0] = *(const bf16x8*)&lds[r * 64 + ((ch)     ^ (r & 7)) * 8];
                a[p][1] = *(const bf16x8*)&lds[r * 64 + ((4 + ch) ^ (r & 7)) * 8];
            }
#pragma unroll
            for (int nf = 0; nf < 2; ++nf) {
                const int r = wn * 64 + nf * 32 + fr;
                b[nf][0] = *(const bf16x8*)&lds[8192 + r * 64 + ((ch)     ^ (r & 7)) * 8];
                b[nf][1] = *(const bf16x8*)&lds[8192 + r * 64 + ((4 + ch) ^ (r & 7)) * 8];
            }
#pragma unroll
            for (int p = 0; p < 2; ++p)
#pragma unroll
                for (int nf = 0; nf < 2; ++nf) {
                    acc[p][nf] = __builtin_amdgcn_mfma_f32_32x32x16_bf16(a[p][0], b[nf][0], acc[p][nf], 0, 0, 0);
                    acc[p][nf] = __builtin_amdgcn_mfma_f32_32x32x16_bf16(a[p][0], b[nf][1], acc[p][nf], 0, 0, 0);
                    acc[p][nf] = __builtin_amdgcn_mfma_f32_32x32x16_bf16(a[p][1], b[nf][0], acc[p][nf], 0, 0, 0);
                }
        }
        __syncthreads();
    }

    // epilogue: z = relu(alpha*acc)
    // 32x32 C/D layout: col = lane&31, row = (reg&3) + 8*(reg>>2) + 4*(lane>>5)
#pragma unroll
    for (int p = 0; p < 2; ++p)
#pragma unroll
        for (int nf = 0; nf < 2; ++nf) {
            const int col = n0 + wn * 64 + nf * 32 + fr;
#pragma unroll
            for (int r = 0; r < 16; ++r) {
                const int row = m0 + wm * 64 + p * 32 + (r & 3) + 8 * (r >> 2) + 4 * kp;
                C[(size_t)row * EE + col] = fmaxf(ALPHA * acc[p][nf][r], 0.f);
            }
        }
}

// ---------------- kernel Z: zero the worklist counter ----------------
__global__ void zero_count_kernel(int* __restrict__ count) {
    if (threadIdx.x == 0 && blockIdx.x == 0) count[0] = 0;
}

// ---------------- kernel C: softmax threshold + borderline worklist ----------------
__global__ __launch_bounds__(256)
void softmax_threshold_flag_kernel(float* __restrict__ out,
                                   int* __restrict__ count,
                                   int* __restrict__ worklist)
{
    const int wave = threadIdx.x >> 6;
    const int lane = threadIdx.x & 63;
    const size_t row = (size_t)blockIdx.x * 4 + wave;
    float* p = out + row * EE;

    float z[16];
    float m = 0.f;  // z >= 0 (relu output)
#pragma unroll
    for (int j = 0; j < 4; ++j) {
        float4 v = *(const float4*)(p + j * 256 + lane * 4);
        z[j*4+0] = v.x; z[j*4+1] = v.y; z[j*4+2] = v.z; z[j*4+3] = v.w;
        m = fmaxf(m, fmaxf(fmaxf(v.x, v.y), fmaxf(v.z, v.w)));
    }
#pragma unroll
    for (int off = 32; off >= 1; off >>= 1)
        m = fmaxf(m, __shfl_xor(m, off, 64));

    float e[16];
    float sum = 0.f;
#pragma unroll
    for (int j = 0; j < 16; ++j) {
        e[j] = expf(z[j] - m);
        sum += e[j];
    }
#pragma unroll
    for (int off = 32; off >= 1; off >>= 1)
        sum += __shfl_xor(sum, off, 64);

    const float thr = 0.5f * sum;
    const float T   = m + logf(thr);   // z-space threshold
    int lf = 0;
#pragma unroll
    for (int j = 0; j < 16; ++j)
        lf |= (fabsf(z[j] - T) < TAU) ? 1 : 0;

#pragma unroll
    for (int j = 0; j < 4; ++j) {
        float4 o;
        o.x = (e[j*4+0] > thr) ? 1.f : 0.f;
        o.y = (e[j*4+1] > thr) ? 1.f : 0.f;
        o.z = (e[j*4+2] > thr) ? 1.f : 0.f;
        o.w = (e[j*4+3] > thr) ? 1.f : 0.f;
        *(float4*)(p + j * 256 + lane * 4) = o;
    }
    const int anyf = __any(lf);
    if (anyf && lane == 0) {
        int idx = atomicAdd(count, 1);
        worklist[idx] = (int)row;
    }
}

// ---------------- kernel D1: parallel fp32 z-recompute of worklisted rows ----
__global__ __launch_bounds__(256)
void fixup_z_kernel(const float* __restrict__ node, const float* __restrict__ edge,
                    const int* __restrict__ count, const int* __restrict__ worklist,
                    float* __restrict__ zbuf, int zcap)
{
    __shared__ float sa[DD];
    const int t    = threadIdx.x;
    const int lane = t & 63;
    const int wid  = t >> 6;

    int nwork = count[0];
    if (nwork > zcap) nwork = zcap;
    const int items = nwork * 4;

    for (int item = blockIdx.x; item < items; item += gridDim.x) {
        const int w   = item >> 2;
        const int row = worklist[w];
        const int c0  = (item & 3) * 256;
        const int s   = row / NN;
        const float* a = node + (size_t)row * DD;
        const float* B = edge + (size_t)s * EE * DD;

        __syncthreads();   // protect sa from previous item
        if (t < DD / 4) ((float4*)sa)[t] = ((const float4*)a)[t];
        __syncthreads();

        const float4 va0 = ((const float4*)sa)[lane];
        const float4 va1 = ((const float4*)sa)[64 + lane];

        const int cbase = c0 + wid * 64;
        for (int g = 0; g < 16; ++g) {
            float acc[4];
#pragma unroll
            for (int j = 0; j < 4; ++j) {
                const float* b = B + (size_t)(cbase + g * 4 + j) * DD;
                float4 b0 = *(const float4*)(b + lane * 4);
                float4 b1 = *(const float4*)(b + 256 + lane * 4);
                float av;
                av = va0.x * b0.x;
                av = fmaf(va0.y, b0.y, av);
                av = fmaf(va0.z, b0.z, av);
                av = fmaf(va0.w, b0.w, av);
                av = fmaf(va1.x, b1.x, av);
                av = fmaf(va1.y, b1.y, av);
                av = fmaf(va1.z, b1.z, av);
                av = fmaf(va1.w, b1.w, av);
                acc[j] = av;
            }
#pragma unroll
            for (int off = 32; off >= 1; off >>= 1) {
#pragma unroll
                for (int j = 0; j < 4; ++j)
                    acc[j] += __shfl_xor(acc[j], off, 64);
            }
            if (lane == 0) {
#pragma unroll
                for (int j = 0; j < 4; ++j)
                    zbuf[(size_t)w * EE + cbase + g * 4 + j] = fmaxf(ALPHA * acc[j], 0.f);
            }
        }
    }
}

// ---------------- kernel D2: softmax+threshold of recomputed rows ----------
__global__ __launch_bounds__(256)
void fixup_finish_kernel(const float* __restrict__ zbuf,
                         const int* __restrict__ count, const int* __restrict__ worklist,
                         float* __restrict__ out, int zcap)
{
    const int lane = threadIdx.x & 63;
    const int wid  = threadIdx.x >> 6;
    int nwork = count[0];
    if (nwork > zcap) nwork = zcap;

    for (int w = blockIdx.x * 4 + wid; w < nwork; w += gridDim.x * 4) {
        const int row = worklist[w];
        const float* p = zbuf + (size_t)w * EE;

        float z[16];
        float m = 0.f;
#pragma unroll
        for (int j = 0; j < 4; ++j) {
            float4 v = *(const float4*)(p + j * 256 + lane * 4);
            z[j*4+0] = v.x; z[j*4+1] = v.y; z[j*4+2] = v.z; z[j*4+3] = v.w;
            m = fmaxf(m, fmaxf(fmaxf(v.x, v.y), fmaxf(v.z, v.w)));
        }
#pragma unroll
        for (int off = 32; off >= 1; off >>= 1)
            m = fmaxf(m, __shfl_xor(m, off, 64));

        float e[16], sum = 0.f;
#pragma unroll
        for (int j = 0; j < 16; ++j) { e[j] = expf(z[j] - m); sum += e[j]; }
#pragma unroll
        for (int off = 32; off >= 1; off >>= 1)
            sum += __shfl_xor(sum, off, 64);

        const float thr = 0.5f * sum;
        float* q = out + (size_t)row * EE;
#pragma unroll
        for (int j = 0; j < 4; ++j) {
            float4 o;
            o.x = (e[j*4+0] > thr) ? 1.f : 0.f;
            o.y = (e[j*4+1] > thr) ? 1.f : 0.f;
            o.z = (e[j*4+2] > thr) ? 1.f : 0.f;
            o.w = (e[j*4+3] > thr) ? 1.f : 0.f;
            *(float4*)(q + j * 256 + lane * 4) = o;
        }
    }
}

// ---------------- kernel D3: slow-path fixup for rows beyond zcap ----------
__global__ __launch_bounds__(256)
void fixup2_kernel(const float* __restrict__ node, const float* __restrict__ edge,
                   const int* __restrict__ count, const int* __restrict__ worklist,
                   float* __restrict__ out, int start)
{
    __shared__ float sa[DD];
    __shared__ float zrow[EE];
    __shared__ float red[8];

    const int t    = threadIdx.x;
    const int lane = t & 63;
    const int wid  = t >> 6;
    const int nwork = count[0];

    for (int w = start + blockIdx.x; w < nwork; w += gridDim.x) {
        const int row = worklist[w];
        const int s = row / NN;
        const float* a = node + (size_t)row * DD;
        const float* B = edge + (size_t)s * EE * DD;

        __syncthreads();
        if (t < DD / 4) ((float4*)sa)[t] = ((const float4*)a)[t];
        __syncthreads();

        float4 va0 = ((const float4*)sa)[lane];
        float4 va1 = ((const float4*)sa)[64 + lane];

        for (int c = wid; c < EE; c += 4) {
            const float* b = B + (size_t)c * DD;
            float4 b0 = *(const float4*)(b + lane * 4);
            float4 b1 = *(const float4*)(b + 256 + lane * 4);
            float acc;
            acc = va0.x * b0.x;
            acc = fmaf(va0.y, b0.y, acc);
            acc = fmaf(va0.z, b0.z, acc);
            acc = fmaf(va0.w, b0.w, acc);
            acc = fmaf(va1.x, b1.x, acc);
            acc = fmaf(va1.y, b1.y, acc);
            acc = fmaf(va1.z, b1.z, acc);
            acc = fmaf(va1.w, b1.w, acc);
#pragma unroll
            for (int off = 32; off >= 1; off >>= 1)
                acc += __shfl_xor(acc, off, 64);
            if (lane == 0) zrow[c] = fmaxf(ALPHA * acc, 0.f);
        }
        __syncthreads();

        float z[4], m = 0.f;
#pragma unroll
        for (int j = 0; j < 4; ++j) {
            z[j] = zrow[j * 256 + t];
            m = fmaxf(m, z[j]);
        }
#pragma unroll
        for (int off = 32; off >= 1; off >>= 1)
            m = fmaxf(m, __shfl_xor(m, off, 64));
        if (lane == 0) red[wid] = m;
        __syncthreads();
        m = fmaxf(fmaxf(red[0], red[1]), fmaxf(red[2], red[3]));

        float e[4], sum = 0.f;
#pragma unroll
        for (int j = 0; j < 4; ++j) { e[j] = expf(z[j] - m); sum += e[j]; }
#pragma unroll
        for (int off = 32; off >= 1; off >>= 1)
            sum += __shfl_xor(sum, off, 64);
        if (lane == 0) red[4 + wid] = sum;
        __syncthreads();
        sum = red[4] + red[5] + red[6] + red[7];

        const float thr = 0.5f * sum;
#pragma unroll
        for (int j = 0; j < 4; ++j)
            out[(size_t)row * EE + j * 256 + t] = (e[j] > thr) ? 1.f : 0.f;
        __syncthreads();
    }
}

// ---------------- fallback fp32 path (round-0, verified) ----------------
#define BM 128
#define BN 128
#define BK 16
#define TM 8
#define TN 8

__global__ __launch_bounds__(256, 2)
void gemm_relu_kernel(const float* __restrict__ node,
                      const float* __restrict__ edge,
                      float* __restrict__ out)
{
    const int s  = blockIdx.z;
    const int m0 = blockIdx.y * BM;
    const int n0 = blockIdx.x * BN;

    const float* A = node + (size_t)s * NN * DD;
    const float* B = edge + (size_t)s * EE * DD;
    float*       C = out  + (size_t)s * NN * EE;

    __shared__ float As[BK][BM + 4];
    __shared__ float Bs[BK][BN + 4];

    const int tid = threadIdx.x;
    const int tx  = tid % 16;
    const int ty  = tid / 16;
    const int lrow = tid / 4;
    const int lcol = (tid % 4) * 4;

    float acc[TM][TN];
#pragma unroll
    for (int i = 0; i < TM; ++i)
#pragma unroll
        for (int j = 0; j < TN; ++j) acc[i][j] = 0.f;

    for (int k0 = 0; k0 < DD; k0 += BK) {
#pragma unroll
        for (int p = 0; p < 2; ++p) {
            const int r = lrow + p * 64;
            float4 v = *(const float4*)(A + (size_t)(m0 + r) * DD + k0 + lcol);
            As[lcol + 0][r] = v.x; As[lcol + 1][r] = v.y;
            As[lcol + 2][r] = v.z; As[lcol + 3][r] = v.w;
            float4 w = *(const float4*)(B + (size_t)(n0 + r) * DD + k0 + lcol);
            Bs[lcol + 0][r] = w.x; Bs[lcol + 1][r] = w.y;
            Bs[lcol + 2][r] = w.z; Bs[lcol + 3][r] = w.w;
        }
        __syncthreads();
#pragma unroll
        for (int k = 0; k < BK; ++k) {
            float a[TM], b[TN];
            float4 a0 = *(const float4*)&As[k][ty * 8];
            float4 a1 = *(const float4*)&As[k][ty * 8 + 4];
            a[0]=a0.x; a[1]=a0.y; a[2]=a0.z; a[3]=a0.w;
            a[4]=a1.x; a[5]=a1.y; a[6]=a1.z; a[7]=a1.w;
            float4 b0 = *(const float4*)&Bs[k][tx * 8];
            float4 b1 = *(const float4*)&Bs[k][tx * 8 + 4];
            b[0]=b0.x; b[1]=b0.y; b[2]=b0.z; b[3]=b0.w;
            b[4]=b1.x; b[5]=b1.y; b[6]=b1.z; b[7]=b1.w;
#pragma unroll
            for (int i = 0; i < TM; ++i)
#pragma unroll
                for (int j = 0; j < TN; ++j)
                    acc[i][j] = fmaf(a[i], b[j], acc[i][j]);
        }
        __syncthreads();
    }
#pragma unroll
    for (int i = 0; i < TM; ++i) {
        const size_t row = (size_t)(m0 + ty * 8 + i);
        float4 o0, o1;
        o0.x = fmaxf(ALPHA * acc[i][0], 0.f);
        o0.y = fmaxf(ALPHA * acc[i][1], 0.f);
        o0.z = fmaxf(ALPHA * acc[i][2], 0.f);
        o0.w = fmaxf(ALPHA * acc[i][3], 0.f);
        o1.x = fmaxf(ALPHA * acc[i][4], 0.f);
        o1.y = fmaxf(ALPHA * acc[i][5], 0.f);
        o1.z = fmaxf(ALPHA * acc[i][6], 0.f);
        o1.w = fmaxf(ALPHA * acc[i][7], 0.f);
        *(float4*)(C + row * EE + n0 + tx * 8)     = o0;
        *(float4*)(C + row * EE + n0 + tx * 8 + 4) = o1;
    }
}

__global__ __launch_bounds__(256)
void softmax_threshold_kernel(float* __restrict__ out)
{
    const int wave = threadIdx.x >> 6;
    const int lane = threadIdx.x & 63;
    const size_t row = (size_t)blockIdx.x * 4 + wave;
    float* p = out + row * EE;

    float z[16];
    float m = 0.f;
#pragma unroll
    for (int j = 0; j < 4; ++j) {
        float4 v = *(const float4*)(p + j * 256 + lane * 4);
        z[j*4+0] = v.x; z[j*4+1] = v.y; z[j*4+2] = v.z; z[j*4+3] = v.w;
        m = fmaxf(m, fmaxf(fmaxf(v.x, v.y), fmaxf(v.z, v.w)));
    }
#pragma unroll
    for (int off = 32; off >= 1; off >>= 1)
        m = fmaxf(m, __shfl_xor(m, off, 64));
    float e[16], sum = 0.f;
#pragma unroll
    for (int j = 0; j < 16; ++j) { e[j] = expf(z[j] - m); sum += e[j]; }
#pragma unroll
    for (int off = 32; off >= 1; off >>= 1)
        sum += __shfl_xor(sum, off, 64);
    const float thr = 0.5f * sum;
#pragma unroll
    for (int j = 0; j < 4; ++j) {
        float4 o;
        o.x = (e[j*4+0] > thr) ? 1.f : 0.f;
        o.y = (e[j*4+1] > thr) ? 1.f : 0.f;
        o.z = (e[j*4+2] > thr) ? 1.f : 0.f;
        o.w = (e[j*4+3] > thr) ? 1.f : 0.f;
        *(float4*)(p + j * 256 + lane * 4) = o;
    }
}

// ---------------- launch ----------------
extern "C" void kernel_launch(void* const* d_in, const int* in_sizes, int n_in,
                              void* d_out, int out_size, void* d_ws, size_t ws_size,
                              hipStream_t stream) {
    const float* node = (const float*)d_in[1];  // [S, N, D]
    const float* edge = (const float*)d_in[2];  // [S, E, D]
    float* out = (float*)d_out;                 // [S, N, E]

    const size_t SAe = (size_t)SS * NN * DD;    // node elems
    const size_t SBe = (size_t)SS * EE * DD;    // edge elems
    const size_t split_bytes = (2 * SAe + 2 * SBe) * 2;
    const size_t wl_bytes    = (size_t)(SS * NN + 1) * 4;
    const size_t base_need   = split_bytes + wl_bytes;

    if (ws_size >= base_need) {
        unsigned short* Ah = (unsigned short*)d_ws;
        unsigned short* Al = Ah + SAe;
        unsigned short* Bh = Al + SAe;
        unsigned short* Bl = Bh + SBe;
        int* count    = (int*)(Bl + SBe);
        int* worklist = count + 1;

        // z-scratch for the parallel fixup, after the base region (256B aligned)
        const size_t zoff = (base_need + 255) & ~(size_t)255;
        int zcap = 0;
        if (ws_size > zoff) {
            size_t zc = (ws_size - zoff) / ((size_t)EE * 4);
            zcap = (int)(zc > 4096 ? 4096 : zc);
        }
        float* zbuf = (float*)((char*)d_ws + zoff);

        const int n4 = (int)((SAe + SBe) / 4);
        split_both_kernel<<<(n4 + 255) / 256, 256, 0, stream>>>(node, edge, Ah, Al, Bh, Bl);

        zero_count_kernel<<<1, 64, 0, stream>>>(count);

        dim3 g1(NN / 128, EE / 128, SS);   // (64, 8, 3): m-fastest, A-panel on one XCD
        gemm_mfma_kernel<<<g1, 256, 0, stream>>>(Ah, Al, Bh, Bl, out);

        softmax_threshold_flag_kernel<<<(SS * NN) / 4, 256, 0, stream>>>(out, count, worklist);

        if (zcap > 0) {
            fixup_z_kernel<<<1024, 256, 0, stream>>>(node, edge, count, worklist, zbuf, zcap);
            fixup_finish_kernel<<<64, 256, 0, stream>>>(zbuf, count, worklist, out, zcap);
        }
        // rows beyond zcap (never in practice): slow in-block path
        fixup2_kernel<<<512, 256, 0, stream>>>(node, edge, count, worklist, out, zcap);
    } else {
        dim3 g1(EE / BN, NN / BM, SS);
        gemm_relu_kernel<<<g1, 256, 0, stream>>>(node, edge, out);
        softmax_threshold_kernel<<<(SS * NN) / 4, 256, 0, stream>>>(out);
    }
}